// Round 16
// baseline (64.970 us; speedup 1.0000x reference)
//
#include <hip/hip_runtime.h>

#define VOCAB 4000
#define UNIQ 30000
#define MIDN 12
#define HID 256
#define OUT 768
#define BATCH 16
#define SEQ 2048

#define NXCD 8
#define XCOLS 96            // cols per xcd slice
#define SUBC 16             // cols per sub-slice
#define TCHUNK 2048         // tokens per chunk
#define NCHUNK 16           // 32768 / TCHUNK
#define TPASS 256           // tokens per pass (1024 thr / 4 lanes-per-token)
#define NPASS 8             // TCHUNK / TPASS
#define PLANE 32008         // LDS plane stride: 4000*8 + 8 (bank skew)

typedef __attribute__((ext_vector_type(8))) short short8;   // 8 bf16 = 16B
typedef __attribute__((ext_vector_type(2))) float f32x2;
typedef __attribute__((ext_vector_type(4))) float f32x4;
typedef __attribute__((ext_vector_type(4))) unsigned int u32x4;
typedef __attribute__((ext_vector_type(4))) unsigned short u16x4;

__device__ __forceinline__ float bitsf(unsigned int x) {
    float f; __builtin_memcpy(&f, &x, 4); return f;
}
__device__ __forceinline__ unsigned short f2bf(float f) {
    unsigned int x;
    __builtin_memcpy(&x, &f, 4);
    x += 0x7fff + ((x >> 16) & 1);   // round-to-nearest-even
    return (unsigned short)(x >> 16);
}

// ---------------------------------------------------------------------------
// prep: z<3  -> conv_w LDS-transpose tiles (Wt[s][n][h] = W[s*256+h][n], bf16)
//       z==3 -> build_idsT: idsT[t][16] = {first[u], mid[u][..], last[u],0,0}
//       z>=4 -> conv_e: E fp32 -> Ebf bf16 (same layout)
// ---------------------------------------------------------------------------
__global__ __launch_bounds__(256) void prep(
    const float* __restrict__ W, unsigned short* __restrict__ Wt,
    const int* __restrict__ first, const int* __restrict__ mid,
    const int* __restrict__ last, const int* __restrict__ inv_i,
    short* __restrict__ idsT,
    const float* __restrict__ E, unsigned short* __restrict__ Ebf)
{
    __shared__ float T[32][33];
    if (blockIdx.z < 3) {
        const int s  = blockIdx.z;
        const int n0 = blockIdx.x * 32;
        const int h0 = blockIdx.y * 32;
        const int tx = threadIdx.x & 31;
        const int ty = threadIdx.x >> 5;
        #pragma unroll
        for (int k = 0; k < 4; ++k) {
            int h = ty + 8 * k;
            T[h][tx] = W[(size_t)(s * HID + h0 + h) * OUT + n0 + tx];
        }
        __syncthreads();
        #pragma unroll
        for (int k = 0; k < 4; ++k) {
            int n = ty + 8 * k;
            Wt[(size_t)(s * OUT + n0 + n) * HID + h0 + tx] = f2bf(T[tx][n]);
        }
    } else if (blockIdx.z == 3) {
        int bid2 = blockIdx.y * 24 + blockIdx.x;       // 0..191
        int t = bid2 * 256 + threadIdx.x;
        if (t >= BATCH * SEQ) return;
        int u = inv_i[t];
        int4 m0 = *reinterpret_cast<const int4*>(&mid[u * MIDN]);
        int4 m1 = *reinterpret_cast<const int4*>(&mid[u * MIDN + 4]);
        int4 m2 = *reinterpret_cast<const int4*>(&mid[u * MIDN + 8]);
        short ids[16];
        ids[0]  = (short)first[u];
        ids[1]  = (short)m0.x; ids[2]  = (short)m0.y; ids[3]  = (short)m0.z; ids[4]  = (short)m0.w;
        ids[5]  = (short)m1.x; ids[6]  = (short)m1.y; ids[7]  = (short)m1.z; ids[8]  = (short)m1.w;
        ids[9]  = (short)m2.x; ids[10] = (short)m2.y; ids[11] = (short)m2.z; ids[12] = (short)m2.w;
        ids[13] = (short)last[u];
        ids[14] = 0; ids[15] = 0;
        *reinterpret_cast<short8*>(&idsT[(size_t)t * 16])     = *reinterpret_cast<short8*>(&ids[0]);
        *reinterpret_cast<short8*>(&idsT[(size_t)t * 16 + 8]) = *reinterpret_cast<short8*>(&ids[8]);
    } else {
        // conv_e: 128000 short8-groups over z=4..6
        int bid2 = (blockIdx.z - 4) * 192 + blockIdx.y * 24 + blockIdx.x;
        int i = bid2 * 256 + threadIdx.x;
        if (i >= VOCAB * HID / 8) return;
        f32x4 e0 = *reinterpret_cast<const f32x4*>(&E[(size_t)i * 8]);
        f32x4 e1 = *reinterpret_cast<const f32x4*>(&E[(size_t)i * 8 + 4]);
        short8 v;
        v[0] = (short)f2bf(e0.x); v[1] = (short)f2bf(e0.y);
        v[2] = (short)f2bf(e0.z); v[3] = (short)f2bf(e0.w);
        v[4] = (short)f2bf(e1.x); v[5] = (short)f2bf(e1.y);
        v[6] = (short)f2bf(e1.z); v[7] = (short)f2bf(e1.w);
        *reinterpret_cast<short8*>(&Ebf[(size_t)i * 8]) = v;
    }
}

// ---------------------------------------------------------------------------
// proj_mfma (operand-swapped, BK=32): MFMA-M = output col c, MFMA-N = vocab v.
// D[c][v] += sum_h Wt[s][c][h] * Ebf[v][h].  Lane holds 4 consecutive c for
// one v -> 8-B epilogue stores.  s==1 -> Pmid[sub][v][16]; s in {0,2} -> P.
// ---------------------------------------------------------------------------
__global__ __launch_bounds__(256) void proj_mfma(
    const unsigned short* __restrict__ Ebf,
    const unsigned short* __restrict__ Wt,
    unsigned short* __restrict__ P,        // [8][2][4000][96]
    unsigned short* __restrict__ Pmid)     // [48][4000][16]
{
    const int s     = blockIdx.z;
    const int vbase = blockIdx.x * 128;    // vocab tile (32 tiles, padded 4096)
    const int cbase = blockIdx.y * 128;    // output-col tile (6 tiles)
    const unsigned short* Wts = Wt + (size_t)s * OUT * HID;

    __shared__ short As[128][40];   // A = W cols  (rows = c), 80B pitch
    __shared__ short Bs[128][40];   // B = E rows  (rows = v)

    const int tid  = threadIdx.x;
    const int lane = tid & 63;
    const int w    = tid >> 6;
    const int wm   = w >> 1;
    const int wn   = w & 1;
    const int lo   = lane & 15;
    const int hi   = lane >> 4;

    f32x4 acc[4][4] = {};

    for (int kt = 0; kt < HID; kt += 32) {
        #pragma unroll
        for (int p = 0; p < 2; ++p) {
            int idx = p * 256 + tid;
            int row = idx >> 2;
            int ko  = (idx & 3) * 8;
            short8 v = *reinterpret_cast<const short8*>(
                &Wts[(size_t)(cbase + row) * HID + kt + ko]);
            *reinterpret_cast<short8*>(&As[row][ko]) = v;
        }
        #pragma unroll
        for (int p = 0; p < 2; ++p) {
            int idx = p * 256 + tid;
            int row = idx >> 2;
            int ko  = (idx & 3) * 8;
            int gv  = vbase + row;
            short8 v = {};
            if (gv < VOCAB)
                v = *reinterpret_cast<const short8*>(&Ebf[(size_t)gv * HID + kt + ko]);
            *reinterpret_cast<short8*>(&Bs[row][ko]) = v;
        }
        __syncthreads();

        short8 a[4], b[4];
        #pragma unroll
        for (int f = 0; f < 4; ++f)
            a[f] = *reinterpret_cast<short8*>(&As[wm * 64 + f * 16 + lo][hi * 8]);
        #pragma unroll
        for (int f = 0; f < 4; ++f)
            b[f] = *reinterpret_cast<short8*>(&Bs[wn * 64 + f * 16 + lo][hi * 8]);
        #pragma unroll
        for (int fm = 0; fm < 4; ++fm)
            #pragma unroll
            for (int fn = 0; fn < 4; ++fn)
                acc[fm][fn] = __builtin_amdgcn_mfma_f32_16x16x32_bf16(
                    a[fm], b[fn], acc[fm][fn], 0, 0, 0);
        __syncthreads();
    }

    #pragma unroll
    for (int fm = 0; fm < 4; ++fm) {
        #pragma unroll
        for (int fn = 0; fn < 4; ++fn) {
            const int c0 = cbase + wm * 64 + fm * 16 + hi * 4;
            const int v  = vbase + wn * 64 + fn * 16 + lo;
            if (v < VOCAB) {
                u16x4 vals;
                vals.x = f2bf(acc[fm][fn][0]);
                vals.y = f2bf(acc[fm][fn][1]);
                vals.z = f2bf(acc[fm][fn][2]);
                vals.w = f2bf(acc[fm][fn][3]);
                if (s == 1) {
                    *reinterpret_cast<u16x4*>(
                        &Pmid[((size_t)(c0 >> 4) * VOCAB + v) * SUBC + (c0 & 15)]) = vals;
                } else {
                    const int so = (s == 0) ? 0 : 1;
                    const unsigned int sl = (unsigned int)c0 / XCOLS;
                    const unsigned int cc = (unsigned int)c0 - sl * XCOLS;
                    *reinterpret_cast<u16x4*>(
                        &P[(((size_t)sl * 2 + so) * VOCAB + v) * XCOLS + cc]) = vals;
                }
            }
        }
    }
}

// ---------------------------------------------------------------------------
// token_lds (round-12 winner + ONE change: regular stores instead of
// non-temporal). Persistent blocks (grid=256), xcd-affine; 4-lane groups,
// uint2 LDS mid reads, TPASS=256, NPASS=8, 2-ahead fv/lv+ids pipeline;
// f32x2 pk-add accumulate; hoisted dst; pad-zero fold.
// ---------------------------------------------------------------------------
extern __shared__ char lds_raw[];

__global__ __launch_bounds__(1024) void token_lds(
    const unsigned short* __restrict__ P,      // [8][2][4000][96]
    const unsigned short* __restrict__ Pmid,   // [48][4000][16]
    const short* __restrict__ idsT,            // [32768][16]
    const float* __restrict__ bias,
    float* __restrict__ out)
{
    const int xcd = blockIdx.x & 7;
    const int bi  = blockIdx.x >> 3;           // 0..31

    const int tid = threadIdx.x;
    const int l4  = tid & 3;
    const int grp = tid >> 2;                  // 0..255 token group

    char* myplane = lds_raw + l4 * PLANE;
    const unsigned short* Pbase = P + (size_t)xcd * 2 * VOCAB * XCOLS;

    // pad rows: 32 rows x 96 cols of this xcd (disjoint from token rows)
    if (bi == 0 && tid < 768) {
        int r  = tid / 24;                     // 0..31
        int c4 = tid % 24;
        int b  = r >> 1;
        int row = (r & 1) ? (b * (SEQ + 2) + SEQ + 1) : (b * (SEQ + 2));
        f32x4 z = {};
        *reinterpret_cast<f32x4*>(
            &out[(size_t)row * OUT + xcd * XCOLS + c4 * 4]) = z;
    }

    int cur_sl = -1;

    #pragma unroll 1
    for (int k = 0; k < 3; ++k) {
        const int task = bi * 3 + k;           // 0..95
        const int sl   = task >> 4;            // 0..5
        const int ch   = task & 15;            // chunk

        if (sl != cur_sl) {
            if (cur_sl >= 0) __syncthreads();
            const int sub = xcd * 6 + sl;
            const unsigned short* src = Pmid + (size_t)sub * VOCAB * SUBC;
            #pragma unroll
            for (int i = 0; i < 16; ++i) {
                int idx = i * 1024 + tid;      // 0..16383; need 16000
                if (idx < VOCAB * 4) {
                    int row = idx >> 2;
                    int q   = idx & 3;
                    uint2 v = *reinterpret_cast<const uint2*>(&src[row * SUBC + q * 4]);
                    *reinterpret_cast<uint2*>(lds_raw + q * PLANE + row * 8) = v;
                }
            }
            __syncthreads();
            cur_sl = sl;
        }

        const int csub = sl * SUBC + l4 * 4;
        const int colc = xcd * XCOLS + csub;
        const unsigned short* P0 = Pbase + csub;
        const unsigned short* P2 = Pbase + (size_t)VOCAB * XCOLS + csub;
        const f32x4 bv = *reinterpret_cast<const f32x4*>(&bias[colc]);

        const int t0 = ch * TCHUNK + grp;
        // hoisted output base: row = ch*(SEQ+2) + (grp + p*TPASS) + 1
        float* dstT = out + ((size_t)(ch * (SEQ + 2) + 1 + grp)) * OUT + colc;

#define LDIDS(lo_, hi_, tt_) { \
        const u32x4* _r = reinterpret_cast<const u32x4*>(&idsT[(size_t)(tt_) * 16]); \
        lo_ = _r[0]; hi_ = _r[1]; }

#define GATHER(fv_, lv_, lo_, hi_) { \
        int _fid = (int)((lo_).x & 0xffffu); \
        int _lid = (int)((hi_).z >> 16); \
        fv_ = *reinterpret_cast<const uint2*>(&P0[(size_t)_fid * XCOLS]); \
        lv_ = *reinterpret_cast<const uint2*>(&P2[(size_t)_lid * XCOLS]); }

        u32x4 ilA, ihA, ilB, ihB;
        uint2 fvA, lvA, fvB, lvB;

        // prologue: ids(0), ids(1); fv/lv(0)
        LDIDS(ilA, ihA, t0);
        LDIDS(ilB, ihB, t0 + TPASS);
        GATHER(fvA, lvA, ilA, ihA);

        #pragma unroll
        for (int p = 0; p < NPASS; ++p) {
            const bool even = (p & 1) == 0;
            u32x4 clo = even ? ilA : ilB;
            u32x4 chi = even ? ihA : ihB;
            uint2 cfv = even ? fvA : fvB;
            uint2 clv = even ? lvA : lvB;

            // issue next pass's fv/lv (ids already resident)
            if (p + 1 < NPASS) {
                if (even) { GATHER(fvB, lvB, ilB, ihB); }
                else      { GATHER(fvA, lvA, ilA, ihA); }
            }
            // load ids two passes ahead into the slot just freed
            if (p + 2 < NPASS) {
                if (even) { LDIDS(ilA, ihA, t0 + (p + 2) * TPASS); }
                else      { LDIDS(ilB, ihB, t0 + (p + 2) * TPASS); }
            }

            // 12 mid rows from LDS
            int rid[MIDN];
            rid[0]  = (int)(clo.x >> 16);
            rid[1]  = (int)(clo.y & 0xffffu);
            rid[2]  = (int)(clo.y >> 16);
            rid[3]  = (int)(clo.z & 0xffffu);
            rid[4]  = (int)(clo.z >> 16);
            rid[5]  = (int)(clo.w & 0xffffu);
            rid[6]  = (int)(clo.w >> 16);
            rid[7]  = (int)(chi.x & 0xffffu);
            rid[8]  = (int)(chi.x >> 16);
            rid[9]  = (int)(chi.y & 0xffffu);
            rid[10] = (int)(chi.y >> 16);
            rid[11] = (int)(chi.z & 0xffffu);

            uint2 mv[MIDN];
            #pragma unroll
            for (int m = 0; m < MIDN; ++m)
                mv[m] = *reinterpret_cast<const uint2*>(myplane + rid[m] * 8);

            // packed accumulate (per-lane order identical to scalar version):
            // pairs {lo,hi} fed to f32x2 += -> v_pk_add_f32
            f32x2 acc01 = {bv.x, bv.y};
            f32x2 acc23 = {bv.z, bv.w};
            #pragma unroll
            for (int m = 0; m < MIDN; ++m) {
                f32x2 v0 = {bitsf(mv[m].x << 16), bitsf(mv[m].x & 0xffff0000u)};
                f32x2 v1 = {bitsf(mv[m].y << 16), bitsf(mv[m].y & 0xffff0000u)};
                acc01 += v0;
                acc23 += v1;
            }
            {
                f32x2 v0 = {bitsf(cfv.x << 16), bitsf(cfv.x & 0xffff0000u)};
                f32x2 v1 = {bitsf(cfv.y << 16), bitsf(cfv.y & 0xffff0000u)};
                acc01 += v0; acc23 += v1;
                f32x2 w0 = {bitsf(clv.x << 16), bitsf(clv.x & 0xffff0000u)};
                f32x2 w1 = {bitsf(clv.y << 16), bitsf(clv.y & 0xffff0000u)};
                acc01 += w0; acc23 += w1;
            }

            float* dst = dstT + (size_t)p * (TPASS * OUT);
            f32x4 o = {acc01.x, acc01.y, acc23.x, acc23.y};
            *reinterpret_cast<f32x4*>(dst) = o;   // regular store (A/B vs NT)
        }
#undef LDIDS
#undef GATHER
    }
}

// ---------------------------------------------------------------------------
extern "C" void kernel_launch(void* const* d_in, const int* in_sizes, int n_in,
                              void* d_out, int out_size, void* d_ws, size_t ws_size,
                              hipStream_t stream)
{
    const float* emb    = (const float*)d_in[0];
    const float* head_w = (const float*)d_in[1];
    const float* head_b = (const float*)d_in[2];
    const int*   first  = (const int*)d_in[3];
    const int*   mid    = (const int*)d_in[4];
    const int*   last   = (const int*)d_in[5];
    const int*   inv_i  = (const int*)d_in[6];
    float* out = (float*)d_out;

    char* ws = (char*)d_ws;
    unsigned short* P    = (unsigned short*)ws;               // 12,288,000 B
    unsigned short* Wt   = (unsigned short*)(ws + 12288000);  //  1,179,648 B
    unsigned short* Ebf  = (unsigned short*)(ws + 13467648);  //  2,048,000 B
    unsigned short* Pmid = (unsigned short*)(ws + 15515648);  //  6,144,000 B
    short*          idsT = (short*)(ws + 21659648);           //  1,048,576 B

    dim3 gp(24, 8, 7);   // z<3: conv_w; z==3: build_idsT; z>=4: conv_e
    prep<<<gp, 256, 0, stream>>>(head_w, Wt, first, mid, last, inv_i,
                                 idsT, emb, Ebf);

    dim3 g1(32, 6, 3);   // x: v-tiles, y: col-tiles, z: s
    proj_mfma<<<g1, 256, 0, stream>>>(Ebf, Wt, P, Pmid);

    token_lds<<<256, 1024, 4 * PLANE, stream>>>(P, Pmid, idsT, head_b, out);
}

// Round 17
// 60.105 us; speedup vs baseline: 1.0810x; 1.0810x over previous
//
#include <hip/hip_runtime.h>

#define VOCAB 4000
#define UNIQ 30000
#define MIDN 12
#define HID 256
#define OUT 768
#define BATCH 16
#define SEQ 2048

#define NXCD 8
#define XCOLS 96            // cols per xcd slice
#define SUBC 16             // cols per sub-slice
#define TCHUNK 2048         // tokens per chunk
#define NCHUNK 16           // 32768 / TCHUNK
#define TPASS 256           // tokens per pass (1024 thr / 4 lanes-per-token)
#define NPASS 8             // TCHUNK / TPASS
#define PLANE 32008         // LDS plane stride: 4000*8 + 8 (bank skew)

typedef __attribute__((ext_vector_type(8))) short short8;   // 8 bf16 = 16B
typedef __attribute__((ext_vector_type(2))) float f32x2;
typedef __attribute__((ext_vector_type(4))) float f32x4;
typedef __attribute__((ext_vector_type(4))) unsigned int u32x4;
typedef __attribute__((ext_vector_type(4))) unsigned short u16x4;

__device__ __forceinline__ float bitsf(unsigned int x) {
    float f; __builtin_memcpy(&f, &x, 4); return f;
}
__device__ __forceinline__ unsigned short f2bf(float f) {
    unsigned int x;
    __builtin_memcpy(&x, &f, 4);
    x += 0x7fff + ((x >> 16) & 1);   // round-to-nearest-even
    return (unsigned short)(x >> 16);
}

// ---------------------------------------------------------------------------
// prep: z<3  -> conv_w LDS-transpose tiles (Wt[s][n][h] = W[s*256+h][n], bf16)
//       z==3 -> build_idsT: idsT[t][16] = {first[u], mid[u][..], last[u],0,0}
//       z>=4 -> conv_e: E fp32 -> Ebf bf16 (same layout)
// ---------------------------------------------------------------------------
__global__ __launch_bounds__(256) void prep(
    const float* __restrict__ W, unsigned short* __restrict__ Wt,
    const int* __restrict__ first, const int* __restrict__ mid,
    const int* __restrict__ last, const int* __restrict__ inv_i,
    short* __restrict__ idsT,
    const float* __restrict__ E, unsigned short* __restrict__ Ebf)
{
    __shared__ float T[32][33];
    if (blockIdx.z < 3) {
        const int s  = blockIdx.z;
        const int n0 = blockIdx.x * 32;
        const int h0 = blockIdx.y * 32;
        const int tx = threadIdx.x & 31;
        const int ty = threadIdx.x >> 5;
        #pragma unroll
        for (int k = 0; k < 4; ++k) {
            int h = ty + 8 * k;
            T[h][tx] = W[(size_t)(s * HID + h0 + h) * OUT + n0 + tx];
        }
        __syncthreads();
        #pragma unroll
        for (int k = 0; k < 4; ++k) {
            int n = ty + 8 * k;
            Wt[(size_t)(s * OUT + n0 + n) * HID + h0 + tx] = f2bf(T[tx][n]);
        }
    } else if (blockIdx.z == 3) {
        int bid2 = blockIdx.y * 24 + blockIdx.x;       // 0..191
        int t = bid2 * 256 + threadIdx.x;
        if (t >= BATCH * SEQ) return;
        int u = inv_i[t];
        int4 m0 = *reinterpret_cast<const int4*>(&mid[u * MIDN]);
        int4 m1 = *reinterpret_cast<const int4*>(&mid[u * MIDN + 4]);
        int4 m2 = *reinterpret_cast<const int4*>(&mid[u * MIDN + 8]);
        short ids[16];
        ids[0]  = (short)first[u];
        ids[1]  = (short)m0.x; ids[2]  = (short)m0.y; ids[3]  = (short)m0.z; ids[4]  = (short)m0.w;
        ids[5]  = (short)m1.x; ids[6]  = (short)m1.y; ids[7]  = (short)m1.z; ids[8]  = (short)m1.w;
        ids[9]  = (short)m2.x; ids[10] = (short)m2.y; ids[11] = (short)m2.z; ids[12] = (short)m2.w;
        ids[13] = (short)last[u];
        ids[14] = 0; ids[15] = 0;
        *reinterpret_cast<short8*>(&idsT[(size_t)t * 16])     = *reinterpret_cast<short8*>(&ids[0]);
        *reinterpret_cast<short8*>(&idsT[(size_t)t * 16 + 8]) = *reinterpret_cast<short8*>(&ids[8]);
    } else {
        // conv_e: 128000 short8-groups over z=4..6
        int bid2 = (blockIdx.z - 4) * 192 + blockIdx.y * 24 + blockIdx.x;
        int i = bid2 * 256 + threadIdx.x;
        if (i >= VOCAB * HID / 8) return;
        f32x4 e0 = *reinterpret_cast<const f32x4*>(&E[(size_t)i * 8]);
        f32x4 e1 = *reinterpret_cast<const f32x4*>(&E[(size_t)i * 8 + 4]);
        short8 v;
        v[0] = (short)f2bf(e0.x); v[1] = (short)f2bf(e0.y);
        v[2] = (short)f2bf(e0.z); v[3] = (short)f2bf(e0.w);
        v[4] = (short)f2bf(e1.x); v[5] = (short)f2bf(e1.y);
        v[6] = (short)f2bf(e1.z); v[7] = (short)f2bf(e1.w);
        *reinterpret_cast<short8*>(&Ebf[(size_t)i * 8]) = v;
    }
}

// ---------------------------------------------------------------------------
// proj_mfma (operand-swapped): MFMA-M = output col c, MFMA-N = vocab v.
// D[c][v] += sum_h Wt[s][c][h] * Ebf[v][h].  Lane holds 4 consecutive c for
// one v -> 8-B epilogue stores.  s==1 -> Pmid[sub][v][16]; s in {0,2} -> P.
// ---------------------------------------------------------------------------
__global__ __launch_bounds__(256) void proj_mfma(
    const unsigned short* __restrict__ Ebf,
    const unsigned short* __restrict__ Wt,
    unsigned short* __restrict__ P,        // [8][2][4000][96]
    unsigned short* __restrict__ Pmid)     // [48][4000][16]
{
    const int s     = blockIdx.z;
    const int vbase = blockIdx.x * 128;    // vocab tile (32 tiles, padded 4096)
    const int cbase = blockIdx.y * 128;    // output-col tile (6 tiles)
    const unsigned short* Wts = Wt + (size_t)s * OUT * HID;

    __shared__ short As[128][40];   // A = W cols  (rows = c), 80B pitch
    __shared__ short Bs[128][40];   // B = E rows  (rows = v)

    const int tid  = threadIdx.x;
    const int lane = tid & 63;
    const int w    = tid >> 6;
    const int wm   = w >> 1;
    const int wn   = w & 1;
    const int lo   = lane & 15;
    const int hi   = lane >> 4;

    f32x4 acc[4][4] = {};

    for (int kt = 0; kt < HID; kt += 32) {
        #pragma unroll
        for (int p = 0; p < 2; ++p) {
            int idx = p * 256 + tid;
            int row = idx >> 2;
            int ko  = (idx & 3) * 8;
            short8 v = *reinterpret_cast<const short8*>(
                &Wts[(size_t)(cbase + row) * HID + kt + ko]);
            *reinterpret_cast<short8*>(&As[row][ko]) = v;
        }
        #pragma unroll
        for (int p = 0; p < 2; ++p) {
            int idx = p * 256 + tid;
            int row = idx >> 2;
            int ko  = (idx & 3) * 8;
            int gv  = vbase + row;
            short8 v = {};
            if (gv < VOCAB)
                v = *reinterpret_cast<const short8*>(&Ebf[(size_t)gv * HID + kt + ko]);
            *reinterpret_cast<short8*>(&Bs[row][ko]) = v;
        }
        __syncthreads();

        short8 a[4], b[4];
        #pragma unroll
        for (int f = 0; f < 4; ++f)
            a[f] = *reinterpret_cast<short8*>(&As[wm * 64 + f * 16 + lo][hi * 8]);
        #pragma unroll
        for (int f = 0; f < 4; ++f)
            b[f] = *reinterpret_cast<short8*>(&Bs[wn * 64 + f * 16 + lo][hi * 8]);
        #pragma unroll
        for (int fm = 0; fm < 4; ++fm)
            #pragma unroll
            for (int fn = 0; fn < 4; ++fn)
                acc[fm][fn] = __builtin_amdgcn_mfma_f32_16x16x32_bf16(
                    a[fm], b[fn], acc[fm][fn], 0, 0, 0);
        __syncthreads();
    }

    #pragma unroll
    for (int fm = 0; fm < 4; ++fm) {
        #pragma unroll
        for (int fn = 0; fn < 4; ++fn) {
            const int c0 = cbase + wm * 64 + fm * 16 + hi * 4;
            const int v  = vbase + wn * 64 + fn * 16 + lo;
            if (v < VOCAB) {
                u16x4 vals;
                vals.x = f2bf(acc[fm][fn][0]);
                vals.y = f2bf(acc[fm][fn][1]);
                vals.z = f2bf(acc[fm][fn][2]);
                vals.w = f2bf(acc[fm][fn][3]);
                if (s == 1) {
                    *reinterpret_cast<u16x4*>(
                        &Pmid[((size_t)(c0 >> 4) * VOCAB + v) * SUBC + (c0 & 15)]) = vals;
                } else {
                    const int so = (s == 0) ? 0 : 1;
                    const unsigned int sl = (unsigned int)c0 / XCOLS;
                    const unsigned int cc = (unsigned int)c0 - sl * XCOLS;
                    *reinterpret_cast<u16x4*>(
                        &P[(((size_t)sl * 2 + so) * VOCAB + v) * XCOLS + cc]) = vals;
                }
            }
        }
    }
}

// ---------------------------------------------------------------------------
// token_lds (round-12 winner, verbatim): persistent blocks (grid=256),
// xcd-affine; 4-lane groups, uint2 LDS mid reads, TPASS=256, NPASS=8,
// 2-ahead fv/lv+ids pipeline; f32x2 pk-add accumulate; hoisted dst;
// NON-TEMPORAL stores (A/B r16 showed regular stores cost ~5 us);
// pad-zero fold.
// ---------------------------------------------------------------------------
extern __shared__ char lds_raw[];

__global__ __launch_bounds__(1024) void token_lds(
    const unsigned short* __restrict__ P,      // [8][2][4000][96]
    const unsigned short* __restrict__ Pmid,   // [48][4000][16]
    const short* __restrict__ idsT,            // [32768][16]
    const float* __restrict__ bias,
    float* __restrict__ out)
{
    const int xcd = blockIdx.x & 7;
    const int bi  = blockIdx.x >> 3;           // 0..31

    const int tid = threadIdx.x;
    const int l4  = tid & 3;
    const int grp = tid >> 2;                  // 0..255 token group

    char* myplane = lds_raw + l4 * PLANE;
    const unsigned short* Pbase = P + (size_t)xcd * 2 * VOCAB * XCOLS;

    // pad rows: 32 rows x 96 cols of this xcd (disjoint from token rows)
    if (bi == 0 && tid < 768) {
        int r  = tid / 24;                     // 0..31
        int c4 = tid % 24;
        int b  = r >> 1;
        int row = (r & 1) ? (b * (SEQ + 2) + SEQ + 1) : (b * (SEQ + 2));
        f32x4 z = {};
        *reinterpret_cast<f32x4*>(
            &out[(size_t)row * OUT + xcd * XCOLS + c4 * 4]) = z;
    }

    int cur_sl = -1;

    #pragma unroll 1
    for (int k = 0; k < 3; ++k) {
        const int task = bi * 3 + k;           // 0..95
        const int sl   = task >> 4;            // 0..5
        const int ch   = task & 15;            // chunk

        if (sl != cur_sl) {
            if (cur_sl >= 0) __syncthreads();
            const int sub = xcd * 6 + sl;
            const unsigned short* src = Pmid + (size_t)sub * VOCAB * SUBC;
            #pragma unroll
            for (int i = 0; i < 16; ++i) {
                int idx = i * 1024 + tid;      // 0..16383; need 16000
                if (idx < VOCAB * 4) {
                    int row = idx >> 2;
                    int q   = idx & 3;
                    uint2 v = *reinterpret_cast<const uint2*>(&src[row * SUBC + q * 4]);
                    *reinterpret_cast<uint2*>(lds_raw + q * PLANE + row * 8) = v;
                }
            }
            __syncthreads();
            cur_sl = sl;
        }

        const int csub = sl * SUBC + l4 * 4;
        const int colc = xcd * XCOLS + csub;
        const unsigned short* P0 = Pbase + csub;
        const unsigned short* P2 = Pbase + (size_t)VOCAB * XCOLS + csub;
        const f32x4 bv = *reinterpret_cast<const f32x4*>(&bias[colc]);

        const int t0 = ch * TCHUNK + grp;
        // hoisted output base: row = ch*(SEQ+2) + (grp + p*TPASS) + 1
        float* dstT = out + ((size_t)(ch * (SEQ + 2) + 1 + grp)) * OUT + colc;

#define LDIDS(lo_, hi_, tt_) { \
        const u32x4* _r = reinterpret_cast<const u32x4*>(&idsT[(size_t)(tt_) * 16]); \
        lo_ = _r[0]; hi_ = _r[1]; }

#define GATHER(fv_, lv_, lo_, hi_) { \
        int _fid = (int)((lo_).x & 0xffffu); \
        int _lid = (int)((hi_).z >> 16); \
        fv_ = *reinterpret_cast<const uint2*>(&P0[(size_t)_fid * XCOLS]); \
        lv_ = *reinterpret_cast<const uint2*>(&P2[(size_t)_lid * XCOLS]); }

        u32x4 ilA, ihA, ilB, ihB;
        uint2 fvA, lvA, fvB, lvB;

        // prologue: ids(0), ids(1); fv/lv(0)
        LDIDS(ilA, ihA, t0);
        LDIDS(ilB, ihB, t0 + TPASS);
        GATHER(fvA, lvA, ilA, ihA);

        #pragma unroll
        for (int p = 0; p < NPASS; ++p) {
            const bool even = (p & 1) == 0;
            u32x4 clo = even ? ilA : ilB;
            u32x4 chi = even ? ihA : ihB;
            uint2 cfv = even ? fvA : fvB;
            uint2 clv = even ? lvA : lvB;

            // issue next pass's fv/lv (ids already resident)
            if (p + 1 < NPASS) {
                if (even) { GATHER(fvB, lvB, ilB, ihB); }
                else      { GATHER(fvA, lvA, ilA, ihA); }
            }
            // load ids two passes ahead into the slot just freed
            if (p + 2 < NPASS) {
                if (even) { LDIDS(ilA, ihA, t0 + (p + 2) * TPASS); }
                else      { LDIDS(ilB, ihB, t0 + (p + 2) * TPASS); }
            }

            // 12 mid rows from LDS
            int rid[MIDN];
            rid[0]  = (int)(clo.x >> 16);
            rid[1]  = (int)(clo.y & 0xffffu);
            rid[2]  = (int)(clo.y >> 16);
            rid[3]  = (int)(clo.z & 0xffffu);
            rid[4]  = (int)(clo.z >> 16);
            rid[5]  = (int)(clo.w & 0xffffu);
            rid[6]  = (int)(clo.w >> 16);
            rid[7]  = (int)(chi.x & 0xffffu);
            rid[8]  = (int)(chi.x >> 16);
            rid[9]  = (int)(chi.y & 0xffffu);
            rid[10] = (int)(chi.y >> 16);
            rid[11] = (int)(chi.z & 0xffffu);

            uint2 mv[MIDN];
            #pragma unroll
            for (int m = 0; m < MIDN; ++m)
                mv[m] = *reinterpret_cast<const uint2*>(myplane + rid[m] * 8);

            // packed accumulate (per-lane order identical to scalar version):
            // pairs {lo,hi} fed to f32x2 += -> v_pk_add_f32
            f32x2 acc01 = {bv.x, bv.y};
            f32x2 acc23 = {bv.z, bv.w};
            #pragma unroll
            for (int m = 0; m < MIDN; ++m) {
                f32x2 v0 = {bitsf(mv[m].x << 16), bitsf(mv[m].x & 0xffff0000u)};
                f32x2 v1 = {bitsf(mv[m].y << 16), bitsf(mv[m].y & 0xffff0000u)};
                acc01 += v0;
                acc23 += v1;
            }
            {
                f32x2 v0 = {bitsf(cfv.x << 16), bitsf(cfv.x & 0xffff0000u)};
                f32x2 v1 = {bitsf(cfv.y << 16), bitsf(cfv.y & 0xffff0000u)};
                acc01 += v0; acc23 += v1;
                f32x2 w0 = {bitsf(clv.x << 16), bitsf(clv.x & 0xffff0000u)};
                f32x2 w1 = {bitsf(clv.y << 16), bitsf(clv.y & 0xffff0000u)};
                acc01 += w0; acc23 += w1;
            }

            float* dst = dstT + (size_t)p * (TPASS * OUT);
            f32x4 o = {acc01.x, acc01.y, acc23.x, acc23.y};
            __builtin_nontemporal_store(o, reinterpret_cast<f32x4*>(dst));
        }
#undef LDIDS
#undef GATHER
    }
}

// ---------------------------------------------------------------------------
extern "C" void kernel_launch(void* const* d_in, const int* in_sizes, int n_in,
                              void* d_out, int out_size, void* d_ws, size_t ws_size,
                              hipStream_t stream)
{
    const float* emb    = (const float*)d_in[0];
    const float* head_w = (const float*)d_in[1];
    const float* head_b = (const float*)d_in[2];
    const int*   first  = (const int*)d_in[3];
    const int*   mid    = (const int*)d_in[4];
    const int*   last   = (const int*)d_in[5];
    const int*   inv_i  = (const int*)d_in[6];
    float* out = (float*)d_out;

    char* ws = (char*)d_ws;
    unsigned short* P    = (unsigned short*)ws;               // 12,288,000 B
    unsigned short* Wt   = (unsigned short*)(ws + 12288000);  //  1,179,648 B
    unsigned short* Ebf  = (unsigned short*)(ws + 13467648);  //  2,048,000 B
    unsigned short* Pmid = (unsigned short*)(ws + 15515648);  //  6,144,000 B
    short*          idsT = (short*)(ws + 21659648);           //  1,048,576 B

    dim3 gp(24, 8, 7);   // z<3: conv_w; z==3: build_idsT; z>=4: conv_e
    prep<<<gp, 256, 0, stream>>>(head_w, Wt, first, mid, last, inv_i,
                                 idsT, emb, Ebf);

    dim3 g1(32, 6, 3);   // x: v-tiles, y: col-tiles, z: s
    proj_mfma<<<g1, 256, 0, stream>>>(Ebf, Wt, P, Pmid);

    token_lds<<<256, 1024, 4 * PLANE, stream>>>(P, Pmid, idsT, head_b, out);
}